// Round 1
// 466.812 us; speedup vs baseline: 1.0602x; 1.0602x over previous
//
#include <hip/hip_runtime.h>
#include <math.h>

#define HIDDEN 1024

typedef _Float16 half8 __attribute__((ext_vector_type(8)));
typedef float floatx4 __attribute__((ext_vector_type(4)));

// out layout (floats): topk_scores, topk_idx, gate_scores, gate_logits
#define OUT_TKS 0
#define OUT_TKI 147456
#define OUT_GS  294912
#define OUT_GL  5013504

// ws layout: WH = 65536 f16 (128KB) | WL = 65536 f16 (128KB) | QL = 512 f32
// WH/WL are in MFMA B-fragment order: idx = ((c*4+nt)*64 + lane)*8 + j
//   expert e = nt*16 + (lane&15), k = c*32 + (lane>>4)*8 + j
#define QL_FOFF 65536   // float offset of QL (after 65536 f16 *2 arrays = 65536 floats)

// blocks 0..63: split W_vis into f16 hi/lo fragment-ordered arrays
// blocks 64..71: query logits (8 x 64)
__global__ __launch_bounds__(256) void prep_kernel(
    const float* __restrict__ query_emb, const float* __restrict__ W_gate,
    float* __restrict__ ws) {
  const int bid = blockIdx.x, tid = threadIdx.x;
  if (bid < 64) {
    _Float16* WH = (_Float16*)ws;
    _Float16* WL = WH + 65536;
    const int base = (bid * 256 + tid) * 4;
    #pragma unroll
    for (int u = 0; u < 4; ++u) {
      const int idx = base + u;
      const int j  = idx & 7;
      const int L  = (idx >> 3) & 63;
      const int nt = (idx >> 9) & 3;
      const int c  = idx >> 11;
      const int e  = nt * 16 + (L & 15);
      const int k  = c * 32 + (L >> 4) * 8 + j;
      const float w = W_gate[e * 2048 + k];
      const _Float16 hi = (_Float16)w;            // RNE
      const float hif = (float)hi;
      WH[idx] = hi;
      WL[idx] = (_Float16)((w - hif) * 2048.0f);  // scaled: stays normal in f16
    }
  } else {
    const int b = bid - 64;                // 0..7
    const int e = tid >> 2, qq = tid & 3;  // expert, quarter of K
    const float* qp = query_emb + b * 1024 + qq * 256;
    const float* wp = W_gate + e * 2048 + 1024 + qq * 256;
    float s = 0.f;
    #pragma unroll 4
    for (int j = 0; j < 256; j += 4) {
      const float4 a = *(const float4*)(qp + j);
      const float4 w = *(const float4*)(wp + j);
      s += a.x * w.x + a.y * w.y + a.z * w.z + a.w * w.w;
    }
    s += __shfl_xor(s, 1);
    s += __shfl_xor(s, 2);
    if (qq == 0) ws[QL_FOFF + b * 64 + e] = s;
  }
}

// Wave-independent MFMA router: each wave owns 16 tokens x 64 experts.
// No LDS, no barriers.
// Register software pipeline: A (HBM) prefetched 2 iterations deep,
// B fragments (L2-resident ws arrays) prefetched 1 iteration deep, so every
// vmcnt wait is COUNTED (leaves the 10 future-iteration loads in flight)
// instead of draining the queue each iteration.
// fp32 = f16hi + f16lo*2^-11;  A.B = Ah.Bh + 2^-11*(Ah.Bl' + Al'.Bh)
__global__ __launch_bounds__(128) void router_main(
    const float* __restrict__ vis, const float* __restrict__ ws,
    float* __restrict__ out) {
  const int tid = threadIdx.x;
  const int L  = tid & 63;         // lane
  const int wv = tid >> 6;         // wave in block (0..1)
  const int m  = L & 15;           // A-frag row / C-frag expert col
  const int q  = L >> 4;           // quad
  const long t0 = (long)blockIdx.x * 32 + wv * 16;
  const _Float16* WH = (const _Float16*)ws;
  const _Float16* WL = WH + 65536;
  const float* QL = ws + QL_FOFF;

  const float* abase = vis + (t0 + m) * HIDDEN + q * 8;
  const int fo = L * 8;            // lane offset into fragment arrays (f16 units)

  floatx4 acc[4], accx[4];
  #pragma unroll
  for (int nt = 0; nt < 4; ++nt) {
    acc[nt]  = (floatx4){0.f, 0.f, 0.f, 0.f};
    accx[nt] = (floatx4){0.f, 0.f, 0.f, 0.f};
  }

  // ---- pipeline prologue ----
  // A for c=0 (current) and c=1 (next); B for c=0 (current)
  float4 a0c = *(const float4*)(abase);
  float4 a1c = *(const float4*)(abase + 4);
  float4 a0n = *(const float4*)(abase + 32);
  float4 a1n = *(const float4*)(abase + 36);
  half8 bh0 = *(const half8*)(WH + fo);
  half8 bh1 = *(const half8*)(WH + fo + 512);
  half8 bh2 = *(const half8*)(WH + fo + 1024);
  half8 bh3 = *(const half8*)(WH + fo + 1536);
  half8 bl0 = *(const half8*)(WL + fo);
  half8 bl1 = *(const half8*)(WL + fo + 512);
  half8 bl2 = *(const half8*)(WL + fo + 1024);
  half8 bl3 = *(const half8*)(WL + fo + 1536);

  #pragma unroll 2
  for (int c = 0; c < 32; ++c) {
    // issue A(c+2)  (tail: reload current chunk, harmless L1 hit)
    const int c2 = (c < 30) ? (c + 2) : c;
    const float* ap2 = abase + c2 * 32;
    const float4 f0 = *(const float4*)ap2;
    const float4 f1 = *(const float4*)(ap2 + 4);

    // issue B(c+1)  (tail: reload current chunk, harmless L1 hit)
    const int c1 = (c < 31) ? (c + 1) : c;
    const _Float16* whp = WH + c1 * 2048 + fo;
    const _Float16* wlp = WL + c1 * 2048 + fo;
    const half8 nh0 = *(const half8*)(whp);
    const half8 nh1 = *(const half8*)(whp + 512);
    const half8 nh2 = *(const half8*)(whp + 1024);
    const half8 nh3 = *(const half8*)(whp + 1536);
    const half8 nl0 = *(const half8*)(wlp);
    const half8 nl1 = *(const half8*)(wlp + 512);
    const half8 nl2 = *(const half8*)(wlp + 1024);
    const half8 nl3 = *(const half8*)(wlp + 1536);

    // split current 8 fp32 -> f16 hi + scaled f16 lo
    half8 ah, al;
    {
      const float av[8] = {a0c.x, a0c.y, a0c.z, a0c.w, a1c.x, a1c.y, a1c.z, a1c.w};
      #pragma unroll
      for (int j = 0; j < 8; ++j) {
        const _Float16 h = (_Float16)av[j];
        ah[j] = h;
        al[j] = (_Float16)((av[j] - (float)h) * 2048.0f);
      }
    }

    // MFMAs on current B (same per-nt order as before: bit-identical results)
    acc[0]  = __builtin_amdgcn_mfma_f32_16x16x32_f16(ah, bh0, acc[0],  0, 0, 0);
    accx[0] = __builtin_amdgcn_mfma_f32_16x16x32_f16(ah, bl0, accx[0], 0, 0, 0);
    accx[0] = __builtin_amdgcn_mfma_f32_16x16x32_f16(al, bh0, accx[0], 0, 0, 0);
    acc[1]  = __builtin_amdgcn_mfma_f32_16x16x32_f16(ah, bh1, acc[1],  0, 0, 0);
    accx[1] = __builtin_amdgcn_mfma_f32_16x16x32_f16(ah, bl1, accx[1], 0, 0, 0);
    accx[1] = __builtin_amdgcn_mfma_f32_16x16x32_f16(al, bh1, accx[1], 0, 0, 0);
    acc[2]  = __builtin_amdgcn_mfma_f32_16x16x32_f16(ah, bh2, acc[2],  0, 0, 0);
    accx[2] = __builtin_amdgcn_mfma_f32_16x16x32_f16(ah, bl2, accx[2], 0, 0, 0);
    accx[2] = __builtin_amdgcn_mfma_f32_16x16x32_f16(al, bh2, accx[2], 0, 0, 0);
    acc[3]  = __builtin_amdgcn_mfma_f32_16x16x32_f16(ah, bh3, acc[3],  0, 0, 0);
    accx[3] = __builtin_amdgcn_mfma_f32_16x16x32_f16(ah, bl3, accx[3], 0, 0, 0);
    accx[3] = __builtin_amdgcn_mfma_f32_16x16x32_f16(al, bh3, accx[3], 0, 0, 0);

    // rotate the pipeline registers
    a0c = a0n; a1c = a1n; a0n = f0; a1n = f1;
    bh0 = nh0; bh1 = nh1; bh2 = nh2; bh3 = nh3;
    bl0 = nl0; bl1 = nl1; bl2 = nl2; bl3 = nl3;
  }

  // ---- epilogue ----
  // C-frag: expert = nt*16 + m, token = t0 + q*4 + reg
  const int bq = blockIdx.x / 288;     // 9216 tokens per query row / 32 per block
  float ql[4];
  #pragma unroll
  for (int nt = 0; nt < 4; ++nt) ql[nt] = QL[bq * 64 + nt * 16 + m];

  float* out_tks = out + OUT_TKS;
  float* out_tki = out + OUT_TKI;
  float* out_gs  = out + OUT_GS;
  float* out_gl  = out + OUT_GL;

  #pragma unroll
  for (int i = 0; i < 4; ++i) {
    const long tok = t0 + q * 4 + i;
    float l[4];
    #pragma unroll
    for (int nt = 0; nt < 4; ++nt)
      l[nt] = acc[nt][i] + accx[nt][i] * (1.0f / 2048.0f) + ql[nt];
    #pragma unroll
    for (int nt = 0; nt < 4; ++nt)
      out_gl[tok * 64 + nt * 16 + m] = l[nt];

    float mx = fmaxf(fmaxf(l[0], l[1]), fmaxf(l[2], l[3]));
    mx = fmaxf(mx, __shfl_xor(mx, 1));
    mx = fmaxf(mx, __shfl_xor(mx, 2));
    mx = fmaxf(mx, __shfl_xor(mx, 4));
    mx = fmaxf(mx, __shfl_xor(mx, 8));

    float s[4], ssum = 0.f;
    #pragma unroll
    for (int nt = 0; nt < 4; ++nt) { s[nt] = expf(l[nt] - mx); ssum += s[nt]; }
    ssum += __shfl_xor(ssum, 1);
    ssum += __shfl_xor(ssum, 2);
    ssum += __shfl_xor(ssum, 4);
    ssum += __shfl_xor(ssum, 8);
    const float inv = 1.0f / ssum;
    #pragma unroll
    for (int nt = 0; nt < 4; ++nt) s[nt] *= inv;
    #pragma unroll
    for (int nt = 0; nt < 4; ++nt)
      out_gs[tok * 64 + nt * 16 + m] = s[nt];

    // local top-2 over the 4 experts this lane owns (ids ascending in nt,
    // strict '>' => lowest index wins ties, jax semantics)
    float v1 = s[0], v2 = s[1]; int i1 = m, i2 = 16 + m;
    if (s[1] > v1) { v2 = v1; i2 = i1; v1 = s[1]; i1 = 16 + m; }
    if (s[2] > v1)      { v2 = v1; i2 = i1; v1 = s[2]; i1 = 32 + m; }
    else if (s[2] > v2) { v2 = s[2]; i2 = 32 + m; }
    if (s[3] > v1)      { v2 = v1; i2 = i1; v1 = s[3]; i1 = 48 + m; }
    else if (s[3] > v2) { v2 = s[3]; i2 = 48 + m; }

    // butterfly merge across the 16-lane group
    #pragma unroll
    for (int msk = 1; msk < 16; msk <<= 1) {
      const float w1 = __shfl_xor(v1, msk), w2 = __shfl_xor(v2, msk);
      const int   j1 = __shfl_xor(i1, msk), j2 = __shfl_xor(i2, msk);
      const bool wfirst = (w1 > v1) || (w1 == v1 && j1 < i1);
      if (wfirst) {
        const bool vsec = (v1 > w2) || (v1 == w2 && i1 < j2);
        v2 = vsec ? v1 : w2; i2 = vsec ? i1 : j2;
        v1 = w1; i1 = j1;
      } else {
        const bool wsec = (w1 > v2) || (w1 == v2 && j1 < i2);
        if (wsec) { v2 = w1; i2 = j1; }
      }
    }
    if (m == 0) {
      *(float2*)(out_tks + tok * 2) = make_float2(v1, v2);
      *(float2*)(out_tki + tok * 2) = make_float2((float)i1, (float)i2);
    }
  }
}

extern "C" void kernel_launch(void* const* d_in, const int* in_sizes, int n_in,
                              void* d_out, int out_size, void* d_ws, size_t ws_size,
                              hipStream_t stream) {
  const float* vis   = (const float*)d_in[0];
  const float* query = (const float*)d_in[1];
  const float* wg    = (const float*)d_in[2];
  float* ws = (float*)d_ws;
  float* o  = (float*)d_out;
  hipLaunchKernelGGL(prep_kernel, dim3(72), dim3(256), 0, stream, query, wg, ws);
  hipLaunchKernelGGL(router_main, dim3(2304), dim3(128), 0, stream, vis, ws, o);
}

// Round 2
// 453.040 us; speedup vs baseline: 1.0924x; 1.0304x over previous
//
#include <hip/hip_runtime.h>
#include <math.h>

#define HIDDEN 1024

typedef _Float16 half8 __attribute__((ext_vector_type(8)));
typedef float floatx4 __attribute__((ext_vector_type(4)));
typedef float floatv4 __attribute__((ext_vector_type(4)));

// out layout (floats): topk_scores, topk_idx, gate_scores, gate_logits
#define OUT_TKS 0
#define OUT_TKI 147456
#define OUT_GS  294912
#define OUT_GL  5013504

// ws layout: WH = 65536 f16 (128KB) | WL = 65536 f16 (128KB) | QL = 512 f32
// WH/WL are in MFMA B-fragment order: idx = ((c*4+nt)*64 + lane)*8 + j
//   expert e = nt*16 + (lane&15), k = c*32 + (lane>>4)*8 + j
#define QL_FOFF 65536   // float offset of QL (after 65536 f16 *2 arrays = 65536 floats)

// blocks 0..63: split W_vis into f16 hi/lo fragment-ordered arrays
// blocks 64..71: query logits (8 x 64)
__global__ __launch_bounds__(256) void prep_kernel(
    const float* __restrict__ query_emb, const float* __restrict__ W_gate,
    float* __restrict__ ws) {
  const int bid = blockIdx.x, tid = threadIdx.x;
  if (bid < 64) {
    _Float16* WH = (_Float16*)ws;
    _Float16* WL = WH + 65536;
    const int base = (bid * 256 + tid) * 4;
    #pragma unroll
    for (int u = 0; u < 4; ++u) {
      const int idx = base + u;
      const int j  = idx & 7;
      const int L  = (idx >> 3) & 63;
      const int nt = (idx >> 9) & 3;
      const int c  = idx >> 11;
      const int e  = nt * 16 + (L & 15);
      const int k  = c * 32 + (L >> 4) * 8 + j;
      const float w = W_gate[e * 2048 + k];
      const _Float16 hi = (_Float16)w;            // RNE
      const float hif = (float)hi;
      WH[idx] = hi;
      WL[idx] = (_Float16)((w - hif) * 2048.0f);  // scaled: stays normal in f16
    }
  } else {
    const int b = bid - 64;                // 0..7
    const int e = tid >> 2, qq = tid & 3;  // expert, quarter of K
    const float* qp = query_emb + b * 1024 + qq * 256;
    const float* wp = W_gate + e * 2048 + 1024 + qq * 256;
    float s = 0.f;
    #pragma unroll 4
    for (int j = 0; j < 256; j += 4) {
      const float4 a = *(const float4*)(qp + j);
      const float4 w = *(const float4*)(wp + j);
      s += a.x * w.x + a.y * w.y + a.z * w.z + a.w * w.w;
    }
    s += __shfl_xor(s, 1);
    s += __shfl_xor(s, 2);
    if (qq == 0) ws[QL_FOFF + b * 64 + e] = s;
  }
}

static __device__ __forceinline__ floatv4 ntld4(const float* p) {
  return __builtin_nontemporal_load((const floatv4*)p);
}

// One wave per block; each wave owns 32 tokens x 64 experts (M_rep=2).
// Rationale (r2): the limiter is per-CU memory-request throughput, not
// per-wave latency. So: (a) M_rep=2 halves B-fragment traffic per token
// and makes each iteration heavy (24 MFMA) so depth-1 A prefetch covers;
// (b) A loads + bulk stores are NONTEMPORAL so the streaming vis data
// doesn't thrash L1 and the shared 8KB/iter B slice stays L1-resident;
// (c) grid 2304 x 64thr = exactly 9 waves/CU, VGPR capped at 170 so all
// are resident with perfect balance. Per-iter issue order: B(c) first,
// then A(c+1) -> the B-wait is vmcnt(4) and never drains the A prefetch.
// fp32 = f16hi + f16lo*2^-11;  A.B = Ah.Bh + 2^-11*(Ah.Bl' + Al'.Bh)
__global__ __launch_bounds__(64, 3) void router_main(
    const float* __restrict__ vis, const float* __restrict__ ws,
    float* __restrict__ out) {
  const int L  = threadIdx.x & 63;  // lane
  const int m  = L & 15;            // A-frag row / C-frag expert col
  const int q  = L >> 4;            // quad
  const long t0 = (long)blockIdx.x * 32;
  const _Float16* WH = (const _Float16*)ws;
  const _Float16* WL = WH + 65536;
  const float* QL = ws + QL_FOFF;

  const float* ab0 = vis + (t0 + m) * HIDDEN + q * 8;        // tokens t0..t0+15
  const float* ab1 = ab0 + 16 * HIDDEN;                       // tokens t0+16..t0+31
  const int fo = L * 8;             // lane offset into fragment arrays (f16 units)

  floatx4 acc[2][4], accx[2][4];
  #pragma unroll
  for (int mf = 0; mf < 2; ++mf)
    #pragma unroll
    for (int nt = 0; nt < 4; ++nt) {
      acc[mf][nt]  = (floatx4){0.f, 0.f, 0.f, 0.f};
      accx[mf][nt] = (floatx4){0.f, 0.f, 0.f, 0.f};
    }

  // A(0) for both M-fragments
  floatv4 c00 = ntld4(ab0), c01 = ntld4(ab0 + 4);
  floatv4 c10 = ntld4(ab1), c11 = ntld4(ab1 + 4);

  #pragma unroll 2
  for (int c = 0; c < 32; ++c) {
    // B(c): issued FIRST so its wait never drains the A prefetch below
    const _Float16* whp = WH + c * 2048 + fo;
    const _Float16* wlp = WL + c * 2048 + fo;
    half8 bh[4], bl[4];
    #pragma unroll
    for (int nt = 0; nt < 4; ++nt) {
      bh[nt] = *(const half8*)(whp + nt * 512);
      bl[nt] = *(const half8*)(wlp + nt * 512);
    }

    // A(c+1), nontemporal (tail: reload current, harmless)
    const int cn = (c < 31) ? (c + 1) : c;
    const floatv4 n00 = ntld4(ab0 + cn * 32), n01 = ntld4(ab0 + cn * 32 + 4);
    const floatv4 n10 = ntld4(ab1 + cn * 32), n11 = ntld4(ab1 + cn * 32 + 4);

    // split current A -> f16 hi + scaled f16 lo (both fragments)
    half8 ah0, al0, ah1, al1;
    {
      const float a0v[8] = {c00.x, c00.y, c00.z, c00.w, c01.x, c01.y, c01.z, c01.w};
      const float a1v[8] = {c10.x, c10.y, c10.z, c10.w, c11.x, c11.y, c11.z, c11.w};
      #pragma unroll
      for (int j = 0; j < 8; ++j) {
        const _Float16 h0 = (_Float16)a0v[j];
        ah0[j] = h0;
        al0[j] = (_Float16)((a0v[j] - (float)h0) * 2048.0f);
        const _Float16 h1 = (_Float16)a1v[j];
        ah1[j] = h1;
        al1[j] = (_Float16)((a1v[j] - (float)h1) * 2048.0f);
      }
    }

    // 24 MFMAs; per-accumulator op order identical to prior rounds
    #pragma unroll
    for (int nt = 0; nt < 4; ++nt) {
      acc[0][nt]  = __builtin_amdgcn_mfma_f32_16x16x32_f16(ah0, bh[nt], acc[0][nt],  0, 0, 0);
      acc[1][nt]  = __builtin_amdgcn_mfma_f32_16x16x32_f16(ah1, bh[nt], acc[1][nt],  0, 0, 0);
      accx[0][nt] = __builtin_amdgcn_mfma_f32_16x16x32_f16(ah0, bl[nt], accx[0][nt], 0, 0, 0);
      accx[1][nt] = __builtin_amdgcn_mfma_f32_16x16x32_f16(ah1, bl[nt], accx[1][nt], 0, 0, 0);
      accx[0][nt] = __builtin_amdgcn_mfma_f32_16x16x32_f16(al0, bh[nt], accx[0][nt], 0, 0, 0);
      accx[1][nt] = __builtin_amdgcn_mfma_f32_16x16x32_f16(al1, bh[nt], accx[1][nt], 0, 0, 0);
    }

    // rotate A pipeline
    c00 = n00; c01 = n01; c10 = n10; c11 = n11;
  }

  // ---- epilogue ----
  // C-frag: expert = nt*16 + m, token(frag mf) = t0 + mf*16 + q*4 + reg
  const int bq = blockIdx.x / 288;     // 9216 tokens per query row / 32 per block
  float ql[4];
  #pragma unroll
  for (int nt = 0; nt < 4; ++nt) ql[nt] = QL[bq * 64 + nt * 16 + m];

  float* out_tks = out + OUT_TKS;
  float* out_tki = out + OUT_TKI;
  float* out_gs  = out + OUT_GS;
  float* out_gl  = out + OUT_GL;

  #pragma unroll
  for (int mf = 0; mf < 2; ++mf) {
    #pragma unroll
    for (int i = 0; i < 4; ++i) {
      const long tok = t0 + mf * 16 + q * 4 + i;
      float l[4];
      #pragma unroll
      for (int nt = 0; nt < 4; ++nt)
        l[nt] = acc[mf][nt][i] + accx[mf][nt][i] * (1.0f / 2048.0f) + ql[nt];
      #pragma unroll
      for (int nt = 0; nt < 4; ++nt)
        __builtin_nontemporal_store(l[nt], out_gl + tok * 64 + nt * 16 + m);

      float mx = fmaxf(fmaxf(l[0], l[1]), fmaxf(l[2], l[3]));
      mx = fmaxf(mx, __shfl_xor(mx, 1));
      mx = fmaxf(mx, __shfl_xor(mx, 2));
      mx = fmaxf(mx, __shfl_xor(mx, 4));
      mx = fmaxf(mx, __shfl_xor(mx, 8));

      float s[4], ssum = 0.f;
      #pragma unroll
      for (int nt = 0; nt < 4; ++nt) { s[nt] = expf(l[nt] - mx); ssum += s[nt]; }
      ssum += __shfl_xor(ssum, 1);
      ssum += __shfl_xor(ssum, 2);
      ssum += __shfl_xor(ssum, 4);
      ssum += __shfl_xor(ssum, 8);
      const float inv = 1.0f / ssum;
      #pragma unroll
      for (int nt = 0; nt < 4; ++nt) s[nt] *= inv;
      #pragma unroll
      for (int nt = 0; nt < 4; ++nt)
        __builtin_nontemporal_store(s[nt], out_gs + tok * 64 + nt * 16 + m);

      // local top-2 over the 4 experts this lane owns (ids ascending in nt,
      // strict '>' => lowest index wins ties, jax semantics)
      float v1 = s[0], v2 = s[1]; int i1 = m, i2 = 16 + m;
      if (s[1] > v1) { v2 = v1; i2 = i1; v1 = s[1]; i1 = 16 + m; }
      if (s[2] > v1)      { v2 = v1; i2 = i1; v1 = s[2]; i1 = 32 + m; }
      else if (s[2] > v2) { v2 = s[2]; i2 = 32 + m; }
      if (s[3] > v1)      { v2 = v1; i2 = i1; v1 = s[3]; i1 = 48 + m; }
      else if (s[3] > v2) { v2 = s[3]; i2 = 48 + m; }

      // butterfly merge across the 16-lane group
      #pragma unroll
      for (int msk = 1; msk < 16; msk <<= 1) {
        const float w1 = __shfl_xor(v1, msk), w2 = __shfl_xor(v2, msk);
        const int   j1 = __shfl_xor(i1, msk), j2 = __shfl_xor(i2, msk);
        const bool wfirst = (w1 > v1) || (w1 == v1 && j1 < i1);
        if (wfirst) {
          const bool vsec = (v1 > w2) || (v1 == w2 && i1 < j2);
          v2 = vsec ? v1 : w2; i2 = vsec ? i1 : j2;
          v1 = w1; i1 = j1;
        } else {
          const bool wsec = (w1 > v2) || (w1 == v2 && j1 < i2);
          if (wsec) { v2 = w1; i2 = j1; }
        }
      }
      if (m == 0) {
        *(float2*)(out_tks + tok * 2) = make_float2(v1, v2);
        *(float2*)(out_tki + tok * 2) = make_float2((float)i1, (float)i2);
      }
    }
  }
}

extern "C" void kernel_launch(void* const* d_in, const int* in_sizes, int n_in,
                              void* d_out, int out_size, void* d_ws, size_t ws_size,
                              hipStream_t stream) {
  const float* vis   = (const float*)d_in[0];
  const float* query = (const float*)d_in[1];
  const float* wg    = (const float*)d_in[2];
  float* ws = (float*)d_ws;
  float* o  = (float*)d_out;
  hipLaunchKernelGGL(prep_kernel, dim3(72), dim3(256), 0, stream, query, wg, ws);
  hipLaunchKernelGGL(router_main, dim3(2304), dim3(64), 0, stream, vis, ws, o);
}